// Round 1
// baseline (465.137 us; speedup 1.0000x reference)
//
#include <hip/hip_runtime.h>

#define NB 262144
#define NJ 24

__global__ __launch_bounds__(256) void fk_kernel(
    const float* __restrict__ rot6,   // [NB][NJ][6]
    const float* __restrict__ pos,    // [NB][NJ][3]
    float* __restrict__ coords,       // [NB][NJ][3]
    float* __restrict__ tf)           // [NB][NJ][4][4]
{
    const int b = blockIdx.x * blockDim.x + threadIdx.x;
    if (b >= NB) return;

    constexpr int P[NJ] = {0,0,0,0,1,2,3,4,5,6,7,8,9,9,9,12,13,14,16,17,18,19,20,21};

    // G[j] = 3x4 affine (bottom row implicitly [0,0,0,1]); constant-indexed
    // after full unroll -> stays in registers, compiler tracks liveness.
    float G[NJ][12];

    #pragma unroll
    for (int j = 0; j < NJ; ++j) {
        // ---- load inputs for (b, j) ----
        const float* r6 = rot6 + ((size_t)b * NJ + j) * 6;   // 8B-aligned
        float2 r01 = *(const float2*)(r6 + 0);
        float2 r23 = *(const float2*)(r6 + 2);
        float2 r45 = *(const float2*)(r6 + 4);
        const float a1x = r01.x, a1y = r01.y, a1z = r23.x;
        const float a2x = r23.y, a2y = r45.x, a2z = r45.y;
        const float* pp = pos + ((size_t)b * NJ + j) * 3;
        const float px = pp[0], py = pp[1], pz = pp[2];

        // ---- 6D -> rotation (Gram-Schmidt) ----
        const float inv1 = rsqrtf(a1x*a1x + a1y*a1y + a1z*a1z);
        const float b1x = a1x*inv1, b1y = a1y*inv1, b1z = a1z*inv1;
        const float d  = b1x*a2x + b1y*a2y + b1z*a2z;
        const float c2x = a2x - d*b1x, c2y = a2y - d*b1y, c2z = a2z - d*b1z;
        const float inv2 = rsqrtf(c2x*c2x + c2y*c2y + c2z*c2z);
        const float b2x = c2x*inv2, b2y = c2y*inv2, b2z = c2z*inv2;
        const float b3x = b1y*b2z - b1z*b2y;
        const float b3y = b1z*b2x - b1x*b2z;
        const float b3z = b1x*b2y - b1y*b2x;

        // local transform rows: row r = [rot[r][0..2], pos[r]]
        const float L[12] = { b1x, b1y, b1z, px,
                              b2x, b2y, b2z, py,
                              b3x, b3y, b3z, pz };

        if (j == 0) {
            #pragma unroll
            for (int k = 0; k < 12; ++k) G[0][k] = L[k];
        } else {
            const int p = P[j];   // compile-time constant after unroll
            #pragma unroll
            for (int r = 0; r < 3; ++r) {
                const float g0 = G[p][r*4+0], g1 = G[p][r*4+1];
                const float g2 = G[p][r*4+2], g3 = G[p][r*4+3];
                G[j][r*4+0] = g0*L[0] + g1*L[4] + g2*L[8];
                G[j][r*4+1] = g0*L[1] + g1*L[5] + g2*L[9];
                G[j][r*4+2] = g0*L[2] + g1*L[6] + g2*L[10];
                G[j][r*4+3] = g0*L[3] + g1*L[7] + g2*L[11] + g3;
            }
        }

        // ---- stores ----
        float4* t4 = (float4*)(tf + ((size_t)b * NJ + j) * 16);  // 64B, 16B-aligned
        t4[0] = make_float4(G[j][0], G[j][1], G[j][2],  G[j][3]);
        t4[1] = make_float4(G[j][4], G[j][5], G[j][6],  G[j][7]);
        t4[2] = make_float4(G[j][8], G[j][9], G[j][10], G[j][11]);
        t4[3] = make_float4(0.f, 0.f, 0.f, 1.f);

        float* c = coords + ((size_t)b * NJ + j) * 3;
        c[0] = G[j][3];
        c[1] = G[j][7];
        c[2] = G[j][11];
    }
}

extern "C" void kernel_launch(void* const* d_in, const int* in_sizes, int n_in,
                              void* d_out, int out_size, void* d_ws, size_t ws_size,
                              hipStream_t stream) {
    const float* rot6 = (const float*)d_in[0];  // [B][J][6] fp32
    const float* pos  = (const float*)d_in[1];  // [B][J][3] fp32
    float* coords = (float*)d_out;                       // first output, B*J*3
    float* tf     = (float*)d_out + (size_t)NB * NJ * 3; // second output, B*J*16

    dim3 grid(NB / 256), block(256);
    fk_kernel<<<grid, block, 0, stream>>>(rot6, pos, coords, tf);
}

// Round 2
// 260.667 us; speedup vs baseline: 1.7844x; 1.7844x over previous
//
#include <hip/hip_runtime.h>

#define NB 262144
#define NJ 24
#define TB 256   // batches per block == threads per block

__global__ __launch_bounds__(TB, 3) void fk_kernel(
    const float* __restrict__ rot6,   // [NB][NJ][6]
    const float* __restrict__ pos,    // [NB][NJ][3]
    float* __restrict__ coords,       // [NB][NJ][3]
    float* __restrict__ tf)           // [NB][NJ][4][4]
{
    // per-phase staging: joints (2t, 2t+1) for 256 batches
    __shared__ float4 srot[TB * 3];   // [b'][3] float4 = 12 rot floats (2 joints)
    __shared__ float2 spos[TB * 3];   // [b'][3] float2 = 6  pos floats (2 joints)
    __shared__ float4 stf [TB * 8];   // [b'][8] float4, XOR-swizzled (2 transforms)

    const int tid = threadIdx.x;
    const int b0  = blockIdx.x * TB;

    constexpr int P[NJ] = {0,0,0,0,1,2,3,4,5,6,7,8,9,9,9,12,13,14,16,17,18,19,20,21};

    // global chain state in registers; constant-indexed after full unroll.
    float Gr[NJ][9];   // rotation 3x3, row-major
    float Gt[NJ][3];   // translation

    const float4* __restrict__ grot4 = (const float4*)rot6;   // 36 f4 / batch
    const float2* __restrict__ gpos2 = (const float2*)pos;    // 36 f2 / batch
    float4* __restrict__ gtf4 = (float4*)tf;                  // 96 f4 / batch
    float2* __restrict__ gco2 = (float2*)coords;              // 36 f2 / batch

    #pragma unroll
    for (int t = 0; t < NJ / 2; ++t) {
        // ---- stage inputs (coalesced: consecutive lanes -> consecutive elements) ----
        #pragma unroll
        for (int i = 0; i < 3; ++i) {
            int q  = i * TB + tid;            // [0, 768)
            int bq = q / 3, kq = q - bq * 3;  // batch, float4-within-pair
            srot[q] = grot4[(size_t)(b0 + bq) * 36 + t * 3 + kq];
        }
        #pragma unroll
        for (int i = 0; i < 3; ++i) {
            int q  = i * TB + tid;
            int bq = q / 3, kq = q - bq * 3;
            spos[q] = gpos2[(size_t)(b0 + bq) * 36 + t * 3 + kq];
        }
        __syncthreads();

        // ---- own-batch fragment from LDS (stride 48B/24B: conflict-free) ----
        const float4 r0 = srot[tid * 3 + 0];
        const float4 r1 = srot[tid * 3 + 1];
        const float4 r2 = srot[tid * 3 + 2];
        const float2 p0 = spos[tid * 3 + 0];
        const float2 p1 = spos[tid * 3 + 1];
        const float2 p2 = spos[tid * 3 + 2];

        #pragma unroll
        for (int jj = 0; jj < 2; ++jj) {
            const int j = 2 * t + jj;   // compile-time after unroll
            const float a1x = jj ? r1.z : r0.x;
            const float a1y = jj ? r1.w : r0.y;
            const float a1z = jj ? r2.x : r0.z;
            const float a2x = jj ? r2.y : r0.w;
            const float a2y = jj ? r2.z : r1.x;
            const float a2z = jj ? r2.w : r1.y;
            const float px  = jj ? p1.y : p0.x;
            const float py  = jj ? p2.x : p0.y;
            const float pz  = jj ? p2.y : p1.x;

            // 6D -> rotation (Gram-Schmidt)
            const float inv1 = rsqrtf(a1x*a1x + a1y*a1y + a1z*a1z);
            const float b1x = a1x*inv1, b1y = a1y*inv1, b1z = a1z*inv1;
            const float d   = b1x*a2x + b1y*a2y + b1z*a2z;
            const float c2x = a2x - d*b1x, c2y = a2y - d*b1y, c2z = a2z - d*b1z;
            const float inv2 = rsqrtf(c2x*c2x + c2y*c2y + c2z*c2z);
            const float b2x = c2x*inv2, b2y = c2y*inv2, b2z = c2z*inv2;
            const float b3x = b1y*b2z - b1z*b2y;
            const float b3y = b1z*b2x - b1x*b2z;
            const float b3z = b1x*b2y - b1y*b2x;

            const float L[9]  = { b1x,b1y,b1z, b2x,b2y,b2z, b3x,b3y,b3z };

            if (j == 0) {
                #pragma unroll
                for (int k = 0; k < 9; ++k) Gr[0][k] = L[k];
                Gt[0][0] = px; Gt[0][1] = py; Gt[0][2] = pz;
            } else {
                const int p = P[j];
                #pragma unroll
                for (int r = 0; r < 3; ++r) {
                    const float g0 = Gr[p][r*3+0], g1 = Gr[p][r*3+1], g2 = Gr[p][r*3+2];
                    Gr[j][r*3+0] = g0*L[0] + g1*L[3] + g2*L[6];
                    Gr[j][r*3+1] = g0*L[1] + g1*L[4] + g2*L[7];
                    Gr[j][r*3+2] = g0*L[2] + g1*L[5] + g2*L[8];
                    Gt[j][r]     = g0*px   + g1*py   + g2*pz   + Gt[p][r];
                }
            }

            // transform rows into swizzled LDS tile
            #pragma unroll
            for (int rr = 0; rr < 4; ++rr) {
                const int s = jj * 4 + rr;
                const float4 v = (rr == 3)
                    ? make_float4(0.f, 0.f, 0.f, 1.f)
                    : make_float4(Gr[j][rr*3+0], Gr[j][rr*3+1], Gr[j][rr*3+2], Gt[j][rr]);
                stf[tid * 8 + (s ^ (tid & 7))] = v;
            }
        }

        // coords for this pair: 6 floats, direct (L2 merges partials across phases)
        {
            const size_t cb = (size_t)(b0 + tid) * 36 + t * 3;
            gco2[cb + 0] = make_float2(Gt[2*t][0],   Gt[2*t][1]);
            gco2[cb + 1] = make_float2(Gt[2*t][2],   Gt[2*t+1][0]);
            gco2[cb + 2] = make_float2(Gt[2*t+1][1], Gt[2*t+1][2]);
        }

        __syncthreads();

        // ---- flush transforms: wave-contiguous full 128B lines ----
        #pragma unroll
        for (int i = 0; i < 8; ++i) {
            int q  = i * TB + tid;            // [0, 2048)
            int bp = q >> 3, s = q & 7;
            float4 v = stf[bp * 8 + (s ^ (bp & 7))];
            gtf4[(size_t)(b0 + bp) * 96 + t * 8 + s] = v;
        }
        __syncthreads();
    }
}

extern "C" void kernel_launch(void* const* d_in, const int* in_sizes, int n_in,
                              void* d_out, int out_size, void* d_ws, size_t ws_size,
                              hipStream_t stream) {
    const float* rot6 = (const float*)d_in[0];
    const float* pos  = (const float*)d_in[1];
    float* coords = (float*)d_out;                       // B*J*3
    float* tf     = (float*)d_out + (size_t)NB * NJ * 3; // B*J*16

    fk_kernel<<<dim3(NB / TB), dim3(TB), 0, stream>>>(rot6, pos, coords, tf);
}